// Round 1
// baseline (202808.752 us; speedup 1.0000x reference)
//
#include <hip/hip_runtime.h>
#include <hip/hip_bf16.h>
#include <stdint.h>
#include <stddef.h>

// DARTS RNN cell, MI355X. Round 0: correctness-first persistent cooperative
// kernel. fp32 VALU compute, column-pair-partitioned across 256 wgs,
// 5 grid barriers per timestep (one per DAG level).
//
// T=1024 steps; per step levels:
//   L0: ch0 = [x_t, h] @ W0 (K=1024) -> state0
//   L1: node1 (sigmoid, pred s0)
//   L2: nodes 2(relu),3(relu),4(id), pred s1
//   L3: node5 (tanh, pred s2), node7 (tanh, pred s3)
//   L4: node6 (sigmoid, pred s5), node8 (relu, pred s5), mean(s1..s8) -> h, out[t]
//
// States stored transposed (H, B) in d_ws so lane=b loads/stores coalesce.
// Weight loads are wave-uniform (k scalarized via readfirstlane) -> s_load.

#define TT 1024
#define BB 64
#define HH 512
#define C2H 1024
#define NBLK 256
#define NTHR 256

#define SCOPE __HIP_MEMORY_SCOPE_AGENT

__device__ __forceinline__ void grid_barrier(unsigned* cnt, unsigned* gen) {
    __syncthreads();
    if (threadIdx.x == 0) {
        unsigned g = __hip_atomic_load(gen, __ATOMIC_RELAXED, SCOPE);
        unsigned a = __hip_atomic_fetch_add(cnt, 1u, __ATOMIC_ACQ_REL, SCOPE);
        if (a == NBLK - 1u) {
            __hip_atomic_store(cnt, 0u, __ATOMIC_RELAXED, SCOPE);
            __hip_atomic_fetch_add(gen, 1u, __ATOMIC_RELEASE, SCOPE);
        } else {
            while (__hip_atomic_load(gen, __ATOMIC_RELAXED, SCOPE) == g) {
                __builtin_amdgcn_s_sleep(2);
            }
            (void)__hip_atomic_load(gen, __ATOMIC_ACQUIRE, SCOPE);
        }
    }
    __syncthreads();
}

__device__ __forceinline__ float fsigmoid(float v) {
    return 1.f / (1.f + __expf(-v));
}

// act codes: 0=sigmoid 1=relu 2=tanh 3=identity
__device__ __forceinline__ float factivate(int a, float v) {
    if (a == 0) return fsigmoid(v);
    if (a == 1) return fmaxf(v, 0.f);
    if (a == 2) return tanhf(v);
    return v;
}

// Compute N nodes sharing the same predecessor state sp.
// Each wg owns ch cols {sw, sw+1} (gates) and {sw+512, sw+513} (candidates),
// i.e. state cols sw, sw+1. K=512 split over 4 waves, LDS reduce.
template <int N>
__device__ __forceinline__ void node_group(
    const float* W0p, const float* W1p, const float* W2p,   // (H x 2H) row-major
    const float* __restrict__ sp,                           // pred state (H,B)
    float* d0, float* d1, float* d2,                        // dest states or null
    int a0c, int a1c, int a2c,
    float* res,                                             // optional: s_new per node (valid tid<128)
    int sw, float* red)
{
    const int tid  = threadIdx.x;
    const int lane = tid & 63;
    const int wave = tid >> 6;
    const int kbase = __builtin_amdgcn_readfirstlane(wave) * (HH / 4);

    const float* Wp[3] = {W0p, W1p, W2p};
    float acc[N][4];
#pragma unroll
    for (int n = 0; n < N; ++n) {
        acc[n][0] = acc[n][1] = acc[n][2] = acc[n][3] = 0.f;
    }

    for (int kk = 0; kk < HH / 4; ++kk) {
        const int k = kbase + kk;
        const float v = sp[k * BB + lane];
#pragma unroll
        for (int n = 0; n < N; ++n) {
            const float* wrow = Wp[n] + (size_t)k * C2H;
            const float2 wa = *(const float2*)(wrow + sw);        // gate cols
            const float2 wb = *(const float2*)(wrow + HH + sw);   // candidate cols
            acc[n][0] = fmaf(v, wa.x, acc[n][0]);
            acc[n][1] = fmaf(v, wa.y, acc[n][1]);
            acc[n][2] = fmaf(v, wb.x, acc[n][2]);
            acc[n][3] = fmaf(v, wb.y, acc[n][3]);
        }
    }

#pragma unroll
    for (int n = 0; n < N; ++n)
#pragma unroll
        for (int c = 0; c < 4; ++c)
            red[((wave * N + n) * 4 + c) * 64 + lane] = acc[n][c];
    __syncthreads();

    if (tid < 128) {
        const int j = tid >> 6;          // 0 or 1 -> which of our two state cols
        const int b = tid & 63;
        const int col = sw + j;
        const float spv = sp[col * BB + b];
        float* dsts[3] = {d0, d1, d2};
        const int acts[3] = {a0c, a1c, a2c};
#pragma unroll
        for (int n = 0; n < N; ++n) {
            float sc = 0.f, sh = 0.f;
#pragma unroll
            for (int w = 0; w < 4; ++w) {
                sc += red[((w * N + n) * 4 + j) * 64 + b];
                sh += red[((w * N + n) * 4 + (j + 2)) * 64 + b];
            }
            const float cg = fsigmoid(sc);
            const float hv = factivate(acts[n], sh);
            const float sv = spv + cg * (hv - spv);
            if (dsts[n]) dsts[n][col * BB + b] = sv;
            if (res) res[n] = sv;
        }
    }
    __syncthreads();   // red reusable by next call
}

// L0: ch0 = [x_t ; h] @ W0 (K=1024). Waves 0,1 take x rows 0..511; waves 2,3
// take h rows (W0 rows 512..1023).
__device__ __forceinline__ void level0(
    const float* __restrict__ x, const float* __restrict__ W0,
    const float* __restrict__ hbuf, float* __restrict__ s0,
    int t, int sw, float* red)
{
    const int tid  = threadIdx.x;
    const int lane = tid & 63;
    const int wave = tid >> 6;
    const int wb = __builtin_amdgcn_readfirstlane(wave);

    float a0 = 0.f, a1 = 0.f, a2 = 0.f, a3 = 0.f;
    if (wb < 2) {
        const float* xrow = x + ((size_t)t * BB + lane) * HH;   // x[t][lane][:]
        const int kbase = wb * 256;
        for (int kk = 0; kk < 256; ++kk) {
            const int k = kbase + kk;
            const float v = xrow[k];
            const float* wrow = W0 + (size_t)k * C2H;
            const float2 wa = *(const float2*)(wrow + sw);
            const float2 wc = *(const float2*)(wrow + HH + sw);
            a0 = fmaf(v, wa.x, a0); a1 = fmaf(v, wa.y, a1);
            a2 = fmaf(v, wc.x, a2); a3 = fmaf(v, wc.y, a3);
        }
    } else {
        const int kbase = (wb - 2) * 256;
        for (int kk = 0; kk < 256; ++kk) {
            const int k = kbase + kk;
            const float v = hbuf[k * BB + lane];
            const float* wrow = W0 + (size_t)(k + HH) * C2H;
            const float2 wa = *(const float2*)(wrow + sw);
            const float2 wc = *(const float2*)(wrow + HH + sw);
            a0 = fmaf(v, wa.x, a0); a1 = fmaf(v, wa.y, a1);
            a2 = fmaf(v, wc.x, a2); a3 = fmaf(v, wc.y, a3);
        }
    }

    red[(wave * 4 + 0) * 64 + lane] = a0;
    red[(wave * 4 + 1) * 64 + lane] = a1;
    red[(wave * 4 + 2) * 64 + lane] = a2;
    red[(wave * 4 + 3) * 64 + lane] = a3;
    __syncthreads();

    if (tid < 128) {
        const int j = tid >> 6;
        const int b = tid & 63;
        const int col = sw + j;
        float sc = 0.f, sh = 0.f;
#pragma unroll
        for (int w = 0; w < 4; ++w) {
            sc += red[(w * 4 + j) * 64 + b];
            sh += red[(w * 4 + (j + 2)) * 64 + b];
        }
        const float c0 = fsigmoid(sc);
        const float h0 = tanhf(sh);
        const float hp = hbuf[col * BB + b];
        s0[col * BB + b] = hp + c0 * (h0 - hp);
    }
    __syncthreads();
}

__global__ void __launch_bounds__(NTHR, 1) darts_kernel(
    const float* __restrict__ x,    // (T,B,H)
    const float* __restrict__ W0,   // (2H,2H)
    const float* __restrict__ Ws,   // (8,H,2H)
    float* __restrict__ out,        // T*B*H + B*H
    unsigned* __restrict__ bar,
    float* __restrict__ sbuf,       // states [9][H][B]
    float* __restrict__ hbuf)       // h [H][B]
{
    __shared__ float red[4 * 3 * 4 * 64];   // 12 KB, sized for N=3 groups
    const int tid = threadIdx.x;
    const int sw  = blockIdx.x * 2;         // our two state columns
    unsigned* cnt = bar;
    unsigned* gen = bar + 32;               // separate cache line

#define SB(i) (sbuf + (size_t)(i) * HH * BB)
#define WMAT(i) (Ws + (size_t)(i) * HH * C2H)

    // zero-init h (ws is poisoned each launch)
    if (tid < 128) {
        const int j = tid >> 6, b = tid & 63;
        hbuf[(sw + j) * BB + b] = 0.f;
    }
    grid_barrier(cnt, gen);

    for (int t = 0; t < TT; ++t) {
        level0(x, W0, hbuf, SB(0), t, sw, red);
        grid_barrier(cnt, gen);

        // L1: node1 sigmoid, pred s0 -> s1
        node_group<1>(WMAT(0), nullptr, nullptr, SB(0),
                      SB(1), nullptr, nullptr, 0, 0, 0, nullptr, sw, red);
        grid_barrier(cnt, gen);

        // L2: nodes 2(relu) 3(relu) 4(identity), pred s1 -> s2,s3,s4
        node_group<3>(WMAT(1), WMAT(2), WMAT(3), SB(1),
                      SB(2), SB(3), SB(4), 1, 1, 3, nullptr, sw, red);
        grid_barrier(cnt, gen);

        // L3: node5 tanh pred s2 -> s5 ; node7 tanh pred s3 -> s7
        node_group<1>(WMAT(4), nullptr, nullptr, SB(2),
                      SB(5), nullptr, nullptr, 2, 0, 0, nullptr, sw, red);
        node_group<1>(WMAT(6), nullptr, nullptr, SB(3),
                      SB(7), nullptr, nullptr, 2, 0, 0, nullptr, sw, red);
        grid_barrier(cnt, gen);

        // L4: node6 sigmoid + node8 relu, pred s5; keep results in registers
        float res[2];
        res[0] = 0.f; res[1] = 0.f;
        node_group<2>(WMAT(5), WMAT(7), nullptr, SB(5),
                      nullptr, nullptr, nullptr, 0, 1, 0, res, sw, red);

        if (tid < 128) {
            const int j = tid >> 6, b = tid & 63;
            const int col = sw + j;
            float m = SB(1)[col * BB + b] + SB(2)[col * BB + b]
                    + SB(3)[col * BB + b] + SB(4)[col * BB + b]
                    + SB(5)[col * BB + b] + res[0]
                    + SB(7)[col * BB + b] + res[1];
            m *= 0.125f;
            hbuf[col * BB + b] = m;
            out[((size_t)t * BB + b) * HH + col] = m;
            if (t == TT - 1) {
                out[(size_t)TT * BB * HH + (size_t)b * HH + col] = m;
            }
        }
        grid_barrier(cnt, gen);   // h visible for next step's L0
    }
#undef SB
#undef WMAT
}

extern "C" void kernel_launch(void* const* d_in, const int* in_sizes, int n_in,
                              void* d_out, int out_size, void* d_ws, size_t ws_size,
                              hipStream_t stream) {
    const float* x  = (const float*)d_in[0];
    const float* W0 = (const float*)d_in[1];
    const float* Ws = (const float*)d_in[2];
    float* out = (float*)d_out;

    unsigned char* ws = (unsigned char*)d_ws;
    unsigned* bar = (unsigned*)ws;                          // 1 KB for barrier
    float* sbuf = (float*)(ws + 1024);                      // 9*H*B*4 = 1.18 MB
    float* hbuf = (float*)(ws + 1024 + 9 * HH * BB * 4);    // 128 KB

    hipMemsetAsync(bar, 0, 1024, stream);

    void* args[] = {(void*)&x, (void*)&W0, (void*)&Ws, (void*)&out,
                    (void*)&bar, (void*)&sbuf, (void*)&hbuf};
    hipLaunchCooperativeKernel((const void*)darts_kernel, dim3(NBLK), dim3(NTHR),
                               args, 0, stream);
}

// Round 2
// 115004.480 us; speedup vs baseline: 1.7635x; 1.7635x over previous
//
#include <hip/hip_runtime.h>
#include <hip/hip_bf16.h>
#include <stdint.h>
#include <stddef.h>

// DARTS RNN cell, MI355X. Round 2: weights staged in LDS (80 KB/wg, loaded
// once — LDS is immune to the barrier's L2 invalidation), XCD-aware column
// swizzle so same-64B-line columns live on one XCD (write merge + fetch dedup).
//
// Partition: 256 wgs x 256 thr; wg owns 2 state columns of every matrix.
// 5 grid barriers per timestep (one per DAG level).

#define TT 1024
#define BB 64
#define HH 512
#define C2H 1024
#define NBLK 256
#define NTHR 256

// LDS weight layout: entries e in [0,5120): e<1024 -> W0 row e; else
// m=(e-1024)>>9, k=(e-1024)&511 -> Ws[m] row k. Each entry: 4 floats
// {gate0,gate1,cand0,cand1} for this wg's column pair.
#define NW_ENT 5120
#define W0_OFF 0
#define WS_OFF(m) (4096 + (m) * 2048)

#define SCOPE __HIP_MEMORY_SCOPE_AGENT

__device__ __forceinline__ void grid_barrier(unsigned* cnt, unsigned* gen) {
    __syncthreads();
    if (threadIdx.x == 0) {
        unsigned g = __hip_atomic_load(gen, __ATOMIC_RELAXED, SCOPE);
        unsigned a = __hip_atomic_fetch_add(cnt, 1u, __ATOMIC_ACQ_REL, SCOPE);
        if (a == NBLK - 1u) {
            __hip_atomic_store(cnt, 0u, __ATOMIC_RELAXED, SCOPE);
            __hip_atomic_fetch_add(gen, 1u, __ATOMIC_RELEASE, SCOPE);
        } else {
            while (__hip_atomic_load(gen, __ATOMIC_RELAXED, SCOPE) == g) {
                __builtin_amdgcn_s_sleep(2);
            }
            (void)__hip_atomic_load(gen, __ATOMIC_ACQUIRE, SCOPE);
        }
    }
    __syncthreads();
}

__device__ __forceinline__ float fsigmoid(float v) {
    return 1.f / (1.f + __expf(-v));
}

// act codes: 0=sigmoid 1=relu 2=tanh 3=identity
__device__ __forceinline__ float factivate(int a, float v) {
    if (a == 0) return fsigmoid(v);
    if (a == 1) return fmaxf(v, 0.f);
    if (a == 2) return tanhf(v);
    return v;
}

// Compute N nodes sharing the same predecessor state sp. Weights from LDS.
template <int N>
__device__ __forceinline__ void node_group(
    const float* w0l, const float* w1l, const float* w2l,   // LDS, [k][4]
    const float* __restrict__ sp,                           // pred state (H,B)
    float* d0, float* d1, float* d2,                        // dest states or null
    int a0c, int a1c, int a2c,
    float* res,                                             // s_new per node (tid<128)
    int sw, float* red)
{
    const int tid  = threadIdx.x;
    const int lane = tid & 63;
    const int wave = tid >> 6;
    const int kbase = __builtin_amdgcn_readfirstlane(wave) * (HH / 4);

    const float* Wl[3] = {w0l, w1l, w2l};
    float acc[N][4];
#pragma unroll
    for (int n = 0; n < N; ++n)
        acc[n][0] = acc[n][1] = acc[n][2] = acc[n][3] = 0.f;

#pragma unroll 4
    for (int kk = 0; kk < HH / 4; ++kk) {
        const int k = kbase + kk;
        const float v = sp[k * BB + lane];
#pragma unroll
        for (int n = 0; n < N; ++n) {
            const float4 w = *(const float4*)(Wl[n] + k * 4);
            acc[n][0] = fmaf(v, w.x, acc[n][0]);
            acc[n][1] = fmaf(v, w.y, acc[n][1]);
            acc[n][2] = fmaf(v, w.z, acc[n][2]);
            acc[n][3] = fmaf(v, w.w, acc[n][3]);
        }
    }

#pragma unroll
    for (int n = 0; n < N; ++n)
#pragma unroll
        for (int c = 0; c < 4; ++c)
            red[((wave * N + n) * 4 + c) * 64 + lane] = acc[n][c];
    __syncthreads();

    if (tid < 128) {
        const int j = tid >> 6;          // which of our two state cols
        const int b = tid & 63;
        const int col = sw + j;
        const float spv = sp[col * BB + b];
        float* dsts[3] = {d0, d1, d2};
        const int acts[3] = {a0c, a1c, a2c};
#pragma unroll
        for (int n = 0; n < N; ++n) {
            float sc = 0.f, sh = 0.f;
#pragma unroll
            for (int w = 0; w < 4; ++w) {
                sc += red[((w * N + n) * 4 + j) * 64 + b];
                sh += red[((w * N + n) * 4 + (j + 2)) * 64 + b];
            }
            const float cg = fsigmoid(sc);
            const float hv = factivate(acts[n], sh);
            const float sv = spv + cg * (hv - spv);
            if (dsts[n]) dsts[n][col * BB + b] = sv;
            if (res) res[n] = sv;
        }
    }
    __syncthreads();
}

// L0: ch0 = [x_t ; h] @ W0 (K=1024). Waves 0,1: x rows 0..511; waves 2,3:
// h rows (W0 rows 512..1023). W0 from LDS.
__device__ __forceinline__ void level0(
    const float* __restrict__ x, const float* w0l,
    const float* __restrict__ hbuf, float* __restrict__ s0,
    int t, int sw, float* red)
{
    const int tid  = threadIdx.x;
    const int lane = tid & 63;
    const int wave = tid >> 6;
    const int wb = __builtin_amdgcn_readfirstlane(wave);

    float a0 = 0.f, a1 = 0.f, a2 = 0.f, a3 = 0.f;
    if (wb < 2) {
        const float* xrow = x + ((size_t)t * BB + lane) * HH;
        const int kbase = wb * 256;
#pragma unroll 4
        for (int kk = 0; kk < 256; ++kk) {
            const int k = kbase + kk;
            const float v = xrow[k];
            const float4 w = *(const float4*)(w0l + k * 4);
            a0 = fmaf(v, w.x, a0); a1 = fmaf(v, w.y, a1);
            a2 = fmaf(v, w.z, a2); a3 = fmaf(v, w.w, a3);
        }
    } else {
        const int kbase = (wb - 2) * 256;
#pragma unroll 4
        for (int kk = 0; kk < 256; ++kk) {
            const int k = kbase + kk;
            const float v = hbuf[k * BB + lane];
            const float4 w = *(const float4*)(w0l + (k + HH) * 4);
            a0 = fmaf(v, w.x, a0); a1 = fmaf(v, w.y, a1);
            a2 = fmaf(v, w.z, a2); a3 = fmaf(v, w.w, a3);
        }
    }

    red[(wave * 4 + 0) * 64 + lane] = a0;
    red[(wave * 4 + 1) * 64 + lane] = a1;
    red[(wave * 4 + 2) * 64 + lane] = a2;
    red[(wave * 4 + 3) * 64 + lane] = a3;
    __syncthreads();

    if (tid < 128) {
        const int j = tid >> 6;
        const int b = tid & 63;
        const int col = sw + j;
        float sc = 0.f, sh = 0.f;
#pragma unroll
        for (int w = 0; w < 4; ++w) {
            sc += red[(w * 4 + j) * 64 + b];
            sh += red[(w * 4 + (j + 2)) * 64 + b];
        }
        const float c0 = fsigmoid(sc);
        const float h0 = tanhf(sh);
        const float hp = hbuf[col * BB + b];
        s0[col * BB + b] = hp + c0 * (h0 - hp);
    }
    __syncthreads();
}

__global__ void __launch_bounds__(NTHR, 1) darts_kernel(
    const float* __restrict__ x,    // (T,B,H)
    const float* __restrict__ W0,   // (2H,2H)
    const float* __restrict__ Ws,   // (8,H,2H)
    float* __restrict__ out,        // T*B*H + B*H
    unsigned* __restrict__ bar,
    float* __restrict__ sbuf,       // states [9][H][B]
    float* __restrict__ hbuf)       // h [H][B]
{
    extern __shared__ float wl[];            // 5120*4 floats = 80 KB weights
    __shared__ float red[4 * 3 * 4 * 64];    // 12 KB reduction buffer
    const int tid = threadIdx.x;
    // XCD-aware swizzle: the 8 col-pairs sharing a 64B line -> same XCD
    // (blockIdx%8 is the XCD under round-robin dispatch).
    const int pair = (blockIdx.x & 7) * 32 + (blockIdx.x >> 3);
    const int sw   = pair * 2;
    unsigned* cnt = bar;
    unsigned* gen = bar + 32;                // separate cache line

#define SB(i) (sbuf + (size_t)(i) * HH * BB)

    // One-time: stage this wg's weight columns into LDS.
    for (int e = tid; e < NW_ENT; e += NTHR) {
        const float* src;
        if (e < 1024) {
            src = W0 + (size_t)e * C2H;
        } else {
            const int m = (e - 1024) >> 9;
            const int k = (e - 1024) & 511;
            src = Ws + ((size_t)m * HH + k) * C2H;
        }
        const float2 g = *(const float2*)(src + sw);
        const float2 c = *(const float2*)(src + HH + sw);
        wl[e * 4 + 0] = g.x; wl[e * 4 + 1] = g.y;
        wl[e * 4 + 2] = c.x; wl[e * 4 + 3] = c.y;
    }

    // zero-init h (ws is poisoned each launch)
    if (tid < 128) {
        const int j = tid >> 6, b = tid & 63;
        hbuf[(sw + j) * BB + b] = 0.f;
    }
    grid_barrier(cnt, gen);

    const float* w0l = wl + W0_OFF;

    for (int t = 0; t < TT; ++t) {
        level0(x, w0l, hbuf, SB(0), t, sw, red);
        grid_barrier(cnt, gen);

        // L1: node1 sigmoid, pred s0 -> s1
        node_group<1>(wl + WS_OFF(0), nullptr, nullptr, SB(0),
                      SB(1), nullptr, nullptr, 0, 0, 0, nullptr, sw, red);
        grid_barrier(cnt, gen);

        // L2: nodes 2(relu) 3(relu) 4(identity), pred s1 -> s2,s3,s4
        node_group<3>(wl + WS_OFF(1), wl + WS_OFF(2), wl + WS_OFF(3), SB(1),
                      SB(2), SB(3), SB(4), 1, 1, 3, nullptr, sw, red);
        grid_barrier(cnt, gen);

        // L3: node5 tanh pred s2 -> s5 ; node7 tanh pred s3 -> s7
        node_group<1>(wl + WS_OFF(4), nullptr, nullptr, SB(2),
                      SB(5), nullptr, nullptr, 2, 0, 0, nullptr, sw, red);
        node_group<1>(wl + WS_OFF(6), nullptr, nullptr, SB(3),
                      SB(7), nullptr, nullptr, 2, 0, 0, nullptr, sw, red);
        grid_barrier(cnt, gen);

        // L4: node6 sigmoid + node8 relu, pred s5; results stay in registers
        float res[2] = {0.f, 0.f};
        node_group<2>(wl + WS_OFF(5), wl + WS_OFF(7), nullptr, SB(5),
                      nullptr, nullptr, nullptr, 0, 1, 0, res, sw, red);

        if (tid < 128) {
            const int j = tid >> 6, b = tid & 63;
            const int col = sw + j;
            float m = SB(1)[col * BB + b] + SB(2)[col * BB + b]
                    + SB(3)[col * BB + b] + SB(4)[col * BB + b]
                    + SB(5)[col * BB + b] + res[0]
                    + SB(7)[col * BB + b] + res[1];
            m *= 0.125f;
            hbuf[col * BB + b] = m;
            out[((size_t)t * BB + b) * HH + col] = m;
            if (t == TT - 1) {
                out[(size_t)TT * BB * HH + (size_t)b * HH + col] = m;
            }
        }
        grid_barrier(cnt, gen);   // h visible for next step's L0
    }
#undef SB
}

extern "C" void kernel_launch(void* const* d_in, const int* in_sizes, int n_in,
                              void* d_out, int out_size, void* d_ws, size_t ws_size,
                              hipStream_t stream) {
    const float* x  = (const float*)d_in[0];
    const float* W0 = (const float*)d_in[1];
    const float* Ws = (const float*)d_in[2];
    float* out = (float*)d_out;

    unsigned char* ws = (unsigned char*)d_ws;
    unsigned* bar = (unsigned*)ws;                          // 1 KB barrier
    float* sbuf = (float*)(ws + 1024);                      // 9*H*B*4 = 1.18 MB
    float* hbuf = (float*)(ws + 1024 + 9 * HH * BB * 4);    // 128 KB

    hipMemsetAsync(bar, 0, 1024, stream);

    void* args[] = {(void*)&x, (void*)&W0, (void*)&Ws, (void*)&out,
                    (void*)&bar, (void*)&sbuf, (void*)&hbuf};
    hipLaunchCooperativeKernel((const void*)darts_kernel, dim3(NBLK), dim3(NTHR),
                               args, (NW_ENT * 4 * sizeof(float)), stream);
}